// Round 3
// baseline (768.190 us; speedup 1.0000x reference)
//
#include <hip/hip_runtime.h>

// ---------- types & helpers ----------
typedef __attribute__((ext_vector_type(8))) short sh8;   // 8 x bf16 (4 VGPRs)
typedef __attribute__((ext_vector_type(4))) float f4;    // MFMA accum / float4
typedef __attribute__((ext_vector_type(4))) unsigned int u4;  // 16B clang vector (nontemporal-ok)

__device__ __forceinline__ float bf2f(unsigned short u) {
    union { unsigned int u; float f; } c; c.u = ((unsigned int)u) << 16; return c.f;
}
__device__ __forceinline__ unsigned short f2bf(float f) {
    union { float f; unsigned int u; } c; c.f = f;
    unsigned int x = c.u;
    unsigned int r = (x + 0x7fffu + ((x >> 16) & 1u)) >> 16;   // RNE
    return (unsigned short)r;
}
__device__ __forceinline__ void bfsplit(float x, short& hi, short& lo) {
    unsigned short h = f2bf(x);
    float r = x - bf2f(h);
    hi = (short)h;
    lo = (short)f2bf(r);
}

// H/O live in FEATURE-PANEL layout: 8 panels of [N][16] bf16 (3.2 MB each).
// Panel f holds feats [f*16, f*16+16). Block (bid&7)==f -> XCD f (round-robin
// dispatch) so one panel is L2-resident per XCD during aggregation.

// ---------- CSR build ----------
__global__ void k_zero_cnt(int* cnt, int N) {
    int i = blockIdx.x * 256 + threadIdx.x;
    if (i < N) cnt[i] = 0;
}

__global__ void k_count(const int* __restrict__ dst, int* __restrict__ cnt, int E, int N) {
    int E4 = E >> 2;
    for (int i = blockIdx.x * 256 + threadIdx.x; i < E4; i += gridDim.x * 256) {
        int4 d = ((const int4*)dst)[i];
        if ((unsigned)d.x < (unsigned)N) atomicAdd(&cnt[d.x], 1);
        if ((unsigned)d.y < (unsigned)N) atomicAdd(&cnt[d.y], 1);
        if ((unsigned)d.z < (unsigned)N) atomicAdd(&cnt[d.z], 1);
        if ((unsigned)d.w < (unsigned)N) atomicAdd(&cnt[d.w], 1);
    }
    if (blockIdx.x == 0) {   // remainder edges
        for (int e = (E4 << 2) + threadIdx.x; e < E; e += 256) {
            int d = dst[e];
            if ((unsigned)d < (unsigned)N) atomicAdd(&cnt[d], 1);
        }
    }
}

#define SCAN_B 256
__global__ void k_scan_a(const int* __restrict__ cnt, int* __restrict__ rowptr,
                         int* __restrict__ bsum, float* __restrict__ dis, int N) {
    __shared__ int sh[SCAN_B];
    int t = threadIdx.x, i = blockIdx.x * SCAN_B + t;
    int v = (i < N) ? cnt[i] : 0;
    if (i < N) dis[i] = rsqrtf((float)(v + 1));   // +1 self loop
    sh[t] = v; __syncthreads();
    for (int off = 1; off < SCAN_B; off <<= 1) {
        int x = (t >= off) ? sh[t - off] : 0;
        __syncthreads();
        sh[t] += x;
        __syncthreads();
    }
    int incl = sh[t];
    if (i < N) rowptr[i] = incl - v;
    if (t == SCAN_B - 1) bsum[blockIdx.x] = incl;
}

__global__ void k_scan_b(int* bsum, int NB) {
    __shared__ int sh[512];
    int t = threadIdx.x;
    int v = (t < NB) ? bsum[t] : 0;
    sh[t] = v; __syncthreads();
    for (int off = 1; off < 512; off <<= 1) {
        int x = (t >= off) ? sh[t - off] : 0;
        __syncthreads();
        sh[t] += x;
        __syncthreads();
    }
    if (t < NB) bsum[t] = sh[t] - v;
}

__global__ void k_scan_c(int* __restrict__ rowptr, int* __restrict__ cursor,
                         const int* __restrict__ bsum, int N) {
    int i = blockIdx.x * 256 + threadIdx.x;
    if (i < N) {
        int r = rowptr[i] + bsum[blockIdx.x];
        rowptr[i] = r;
        cursor[i] = r;
    }
}

// dst-range partitioned fill (8 groups round-robin), unchanged this round.
__global__ void k_fill(const int* __restrict__ src, const int* __restrict__ dst,
                       int* __restrict__ cursor, int* __restrict__ csrc, int E, int N) {
    int g = blockIdx.x & 7;
    int j = blockIdx.x >> 3;
    int nb = gridDim.x >> 3;
    int lo = (int)((long long)g * N / 8);
    int hi = (int)((long long)(g + 1) * N / 8);
    int E4 = E >> 2;
    for (int i = j * 256 + threadIdx.x; i < E4; i += nb * 256) {
        int4 d4 = ((const int4*)dst)[i];
        int e = i << 2;
        #pragma unroll
        for (int q = 0; q < 4; ++q) {
            int d = (q == 0) ? d4.x : (q == 1) ? d4.y : (q == 2) ? d4.z : d4.w;
            if (d < lo || d >= hi) continue;
            int s = src[e + q];
            if ((unsigned)s >= (unsigned)N) continue;
            int p = atomicAdd(&cursor[d], 1);
            csrc[p] = s;
        }
    }
    if (blockIdx.x == 0) {   // remainder edges
        for (int e = (E4 << 2) + threadIdx.x; e < E; e += 256) {
            int d = dst[e];
            int s = src[e];
            if ((unsigned)d >= (unsigned)N || (unsigned)s >= (unsigned)N) continue;
            int p = atomicAdd(&cursor[d], 1);
            csrc[p] = s;
        }
    }
}

// ---------- GEMM (layer 1): H(panel bf16) = (X[N][128](fp32) @ W) * dis[row] ----------
__global__ __launch_bounds__(256)
void k_gemm128_a32(const float* __restrict__ X,
                   const float* __restrict__ W,
                   const float* __restrict__ dis,
                   unsigned short* __restrict__ H, int nPairs) {
    int wave = threadIdx.x >> 6;
    int lane = threadIdx.x & 63;
    int ln = lane & 15, quad = lane >> 4;
    int c0 = (wave & 1) * 64;
    int subTile = wave >> 1;
    const size_t Nn = (size_t)nPairs * 32;

    sh8 bh[4][4], blo[4][4];   // [nt][kt]
    #pragma unroll
    for (int nt = 0; nt < 4; ++nt) {
        int col = c0 + nt * 16 + ln;
        #pragma unroll
        for (int kt = 0; kt < 4; ++kt) {
            int k0 = kt * 32 + quad * 8;
            #pragma unroll
            for (int j = 0; j < 8; ++j) {
                short h, l;
                bfsplit(W[(k0 + j) * 128 + col], h, l);
                bh[nt][kt][j] = h; blo[nt][kt][j] = l;
            }
        }
    }

    for (int p = blockIdx.x; p < nPairs; p += gridDim.x) {
        int nodeBase = p * 32 + subTile * 16;
        const float* xrow = X + (nodeBase + ln) * 128 + quad * 8;
        sh8 ah[4], al[4];
        #pragma unroll
        for (int kt = 0; kt < 4; ++kt) {
            f4 v0 = *(const f4*)(xrow + kt * 32);
            f4 v1 = *(const f4*)(xrow + kt * 32 + 4);
            #pragma unroll
            for (int j = 0; j < 4; ++j) {
                short h, l;
                bfsplit(v0[j], h, l); ah[kt][j] = h; al[kt][j] = l;
                bfsplit(v1[j], h, l); ah[kt][j + 4] = h; al[kt][j + 4] = l;
            }
        }

        f4 acc[4] = { {0.f,0.f,0.f,0.f}, {0.f,0.f,0.f,0.f}, {0.f,0.f,0.f,0.f}, {0.f,0.f,0.f,0.f} };
        #pragma unroll
        for (int kt = 0; kt < 4; ++kt)
            #pragma unroll
            for (int nt = 0; nt < 4; ++nt) {
                acc[nt] = __builtin_amdgcn_mfma_f32_16x16x32_bf16(ah[kt], bh[nt][kt], acc[nt], 0, 0, 0);
                acc[nt] = __builtin_amdgcn_mfma_f32_16x16x32_bf16(ah[kt], blo[nt][kt], acc[nt], 0, 0, 0);
                acc[nt] = __builtin_amdgcn_mfma_f32_16x16x32_bf16(al[kt], bh[nt][kt], acc[nt], 0, 0, 0);
            }

        float ds[4];
        #pragma unroll
        for (int r = 0; r < 4; ++r) ds[r] = dis[nodeBase + quad * 4 + r];
        int fpan = (wave & 1) * 4;   // + nt below; col/16
        #pragma unroll
        for (int nt = 0; nt < 4; ++nt) {
            size_t pb = ((size_t)(fpan + nt) * Nn) * 16;
            #pragma unroll
            for (int r = 0; r < 4; ++r)
                H[pb + (size_t)(nodeBase + quad * 4 + r) * 16 + ln] = f2bf(acc[nt][r] * ds[r]);
        }
    }
}

// ---------- GEMM (layers 2,3): H(panel) = (X(panel bf16) @ W) * dis[row] ----------
__global__ __launch_bounds__(256)
void k_gemm128_a16(const unsigned short* __restrict__ X,
                   const float* __restrict__ W,
                   const float* __restrict__ dis,
                   unsigned short* __restrict__ H, int nPairs) {
    int wave = threadIdx.x >> 6;
    int lane = threadIdx.x & 63;
    int ln = lane & 15, quad = lane >> 4;
    int c0 = (wave & 1) * 64;
    int subTile = wave >> 1;
    const size_t Nn = (size_t)nPairs * 32;

    sh8 bh[4][4], blo[4][4];
    #pragma unroll
    for (int nt = 0; nt < 4; ++nt) {
        int col = c0 + nt * 16 + ln;
        #pragma unroll
        for (int kt = 0; kt < 4; ++kt) {
            int k0 = kt * 32 + quad * 8;
            #pragma unroll
            for (int j = 0; j < 8; ++j) {
                short h, l;
                bfsplit(W[(k0 + j) * 128 + col], h, l);
                bh[nt][kt][j] = h; blo[nt][kt][j] = l;
            }
        }
    }

    for (int p = blockIdx.x; p < nPairs; p += gridDim.x) {
        int nodeBase = p * 32 + subTile * 16;
        sh8 a[4];
        #pragma unroll
        for (int kt = 0; kt < 4; ++kt) {
            int feat0 = kt * 32 + quad * 8;
            const unsigned short* ap =
                X + ((size_t)(feat0 >> 4) * Nn + (nodeBase + ln)) * 16 + (feat0 & 15);
            a[kt] = *(const sh8*)ap;
        }

        f4 acc[4] = { {0.f,0.f,0.f,0.f}, {0.f,0.f,0.f,0.f}, {0.f,0.f,0.f,0.f}, {0.f,0.f,0.f,0.f} };
        #pragma unroll
        for (int kt = 0; kt < 4; ++kt)
            #pragma unroll
            for (int nt = 0; nt < 4; ++nt) {
                acc[nt] = __builtin_amdgcn_mfma_f32_16x16x32_bf16(a[kt], bh[nt][kt], acc[nt], 0, 0, 0);
                acc[nt] = __builtin_amdgcn_mfma_f32_16x16x32_bf16(a[kt], blo[nt][kt], acc[nt], 0, 0, 0);
            }

        float ds[4];
        #pragma unroll
        for (int r = 0; r < 4; ++r) ds[r] = dis[nodeBase + quad * 4 + r];
        int fpan = (wave & 1) * 4;
        #pragma unroll
        for (int nt = 0; nt < 4; ++nt) {
            size_t pb = ((size_t)(fpan + nt) * Nn) * 16;
            #pragma unroll
            for (int r = 0; r < 4; ++r)
                H[pb + (size_t)(nodeBase + quad * 4 + r) * 16 + ln] = f2bf(acc[nt][r] * ds[r]);
        }
    }
}

// ---------- Aggregation v5: feature-panel, 2 lanes per node ----------
// Block (bid&7)==f works ONLY on panel f (3.2 MB -> L2-resident on its XCD).
// Each pair of lanes owns one node; lane h owns feats f*16+h*8 .. +7.
// Per edge: one 16B gather per lane (L2 hit). csrc read non-temporally
// (streaming; don't evict the panel). No cross-lane combine needed.
__global__ __launch_bounds__(256)
void k_agg(const unsigned short* __restrict__ H,
           unsigned short* __restrict__ O,
           const float* __restrict__ dis,
           const int* __restrict__ rowptr,
           const int* __restrict__ cnt,
           const int* __restrict__ csrc,
           const float* __restrict__ bias,
           int relu, int N) {
    int f = blockIdx.x & 7;
    int chunk = blockIdx.x >> 3;
    int pairIdx = threadIdx.x >> 1;
    int h = threadIdx.x & 1;
    int n = chunk * 128 + pairIdx;
    if (n >= N) return;

    const unsigned short* P = H + ((size_t)f * N) * 16;   // panel base
    unsigned short*       Q = O + ((size_t)f * N) * 16;

    float a0, a1, a2, a3, a4, a5, a6, a7;
    {   // self loop (H pre-scaled by dis[n]; final *dn gives dn^2)
        u4 v = *(const u4*)(P + (size_t)n * 16 + h * 8);
        a0 = bf2f((unsigned short)v.x);
        a1 = bf2f((unsigned short)(v.x >> 16));
        a2 = bf2f((unsigned short)v.y);
        a3 = bf2f((unsigned short)(v.y >> 16));
        a4 = bf2f((unsigned short)v.z);
        a5 = bf2f((unsigned short)(v.z >> 16));
        a6 = bf2f((unsigned short)v.w);
        a7 = bf2f((unsigned short)(v.w >> 16));
    }

    auto addrow = [&](u4 v) {
        a0 += bf2f((unsigned short)v.x);
        a1 += bf2f((unsigned short)(v.x >> 16));
        a2 += bf2f((unsigned short)v.y);
        a3 += bf2f((unsigned short)(v.y >> 16));
        a4 += bf2f((unsigned short)v.z);
        a5 += bf2f((unsigned short)(v.z >> 16));
        a6 += bf2f((unsigned short)v.w);
        a7 += bf2f((unsigned short)(v.w >> 16));
    };

    int start = rowptr[n];
    int e = cnt[n];
    int i = 0;
    for (; i + 8 <= e; i += 8) {
        int s[8];
        #pragma unroll
        for (int q = 0; q < 8; ++q) s[q] = __builtin_nontemporal_load(&csrc[start + i + q]);
        u4 v[8];
        #pragma unroll
        for (int q = 0; q < 8; ++q) v[q] = *(const u4*)(P + (size_t)s[q] * 16 + h * 8);
        #pragma unroll
        for (int q = 0; q < 8; ++q) addrow(v[q]);
    }
    for (; i < e; ++i) {
        int s = __builtin_nontemporal_load(&csrc[start + i]);
        addrow(*(const u4*)(P + (size_t)s * 16 + h * 8));
    }

    float dn = dis[n];
    f4 b0 = *(const f4*)(bias + f * 16 + h * 8);
    f4 b1 = *(const f4*)(bias + f * 16 + h * 8 + 4);
    a0 = a0 * dn + b0[0]; a1 = a1 * dn + b0[1];
    a2 = a2 * dn + b0[2]; a3 = a3 * dn + b0[3];
    a4 = a4 * dn + b1[0]; a5 = a5 * dn + b1[1];
    a6 = a6 * dn + b1[2]; a7 = a7 * dn + b1[3];
    if (relu) {
        a0 = fmaxf(a0, 0.f); a1 = fmaxf(a1, 0.f);
        a2 = fmaxf(a2, 0.f); a3 = fmaxf(a3, 0.f);
        a4 = fmaxf(a4, 0.f); a5 = fmaxf(a5, 0.f);
        a6 = fmaxf(a6, 0.f); a7 = fmaxf(a7, 0.f);
    }
    u4 ov;
    ov.x = (unsigned int)f2bf(a0) | ((unsigned int)f2bf(a1) << 16);
    ov.y = (unsigned int)f2bf(a2) | ((unsigned int)f2bf(a3) << 16);
    ov.z = (unsigned int)f2bf(a4) | ((unsigned int)f2bf(a5) << 16);
    ov.w = (unsigned int)f2bf(a6) | ((unsigned int)f2bf(a7) << 16);
    __builtin_nontemporal_store(ov, (u4*)(Q + (size_t)n * 16 + h * 8));
}

// ---------- Final head: OUT[N][40](fp32) = X(panel bf16) @ Wl(fp32 split) + bl ----------
__global__ __launch_bounds__(256)
void k_gemm_final(const unsigned short* __restrict__ X,
                  const float* __restrict__ W,     // [128][40]
                  const float* __restrict__ bl,    // [40]
                  float* __restrict__ OUT, int nTiles) {
    int wave = threadIdx.x >> 6;
    int lane = threadIdx.x & 63;
    int ln = lane & 15, quad = lane >> 4;
    int tile = blockIdx.x * 4 + wave;
    if (tile >= nTiles) return;
    const size_t Nn = (size_t)nTiles * 16;

    sh8 bh[3][4], blo[3][4];
    #pragma unroll
    for (int nt = 0; nt < 3; ++nt) {
        int col = nt * 16 + ln;
        bool valid = (col < 40);
        #pragma unroll
        for (int kt = 0; kt < 4; ++kt) {
            int k0 = kt * 32 + quad * 8;
            #pragma unroll
            for (int j = 0; j < 8; ++j) {
                short h = 0, l = 0;
                if (valid) bfsplit(W[(k0 + j) * 40 + col], h, l);
                bh[nt][kt][j] = h; blo[nt][kt][j] = l;
            }
        }
    }

    int nodeBase = tile * 16;
    sh8 a[4];
    #pragma unroll
    for (int kt = 0; kt < 4; ++kt) {
        int feat0 = kt * 32 + quad * 8;
        const unsigned short* ap =
            X + ((size_t)(feat0 >> 4) * Nn + (nodeBase + ln)) * 16 + (feat0 & 15);
        a[kt] = *(const sh8*)ap;
    }

    f4 acc[3] = { {0.f,0.f,0.f,0.f}, {0.f,0.f,0.f,0.f}, {0.f,0.f,0.f,0.f} };
    #pragma unroll
    for (int kt = 0; kt < 4; ++kt)
        #pragma unroll
        for (int nt = 0; nt < 3; ++nt) {
            acc[nt] = __builtin_amdgcn_mfma_f32_16x16x32_bf16(a[kt], bh[nt][kt], acc[nt], 0, 0, 0);
            acc[nt] = __builtin_amdgcn_mfma_f32_16x16x32_bf16(a[kt], blo[nt][kt], acc[nt], 0, 0, 0);
        }

    #pragma unroll
    for (int nt = 0; nt < 3; ++nt) {
        int col = nt * 16 + ln;
        if (col < 40) {
            float bv = bl[col];
            #pragma unroll
            for (int r = 0; r < 4; ++r)
                OUT[(nodeBase + quad * 4 + r) * 40 + col] = acc[nt][r] + bv;
        }
    }
}

// ---------- launch ----------
extern "C" void kernel_launch(void* const* d_in, const int* in_sizes, int n_in,
                              void* d_out, int out_size, void* d_ws, size_t ws_size,
                              hipStream_t stream) {
    const float* x  = (const float*)d_in[0];
    const int*   ei = (const int*)d_in[1];
    const float* W1 = (const float*)d_in[2];
    const float* b1 = (const float*)d_in[3];
    const float* W2 = (const float*)d_in[4];
    const float* b2 = (const float*)d_in[5];
    const float* W3 = (const float*)d_in[6];
    const float* b3 = (const float*)d_in[7];
    const float* Wl = (const float*)d_in[8];
    const float* bl = (const float*)d_in[9];

    const int N = in_sizes[0] / 128;   // 100000
    const int E = in_sizes[1] / 2;     // 1600000
    const int* srcIdx = ei;
    const int* dstIdx = ei + E;

    char* ws = (char*)d_ws;
    size_t off = 0;
    auto alloc = [&](size_t bytes) { void* p = ws + off; off += (bytes + 511) & ~(size_t)511; return p; };
    int*   cnt     = (int*)  alloc((size_t)N * 4);
    int*   rowptr  = (int*)  alloc((size_t)N * 4);
    int*   cursor  = (int*)  alloc((size_t)N * 4);
    float* dis     = (float*)alloc((size_t)N * 4);
    int*   bsum    = (int*)  alloc(512 * 4);
    int*   csrc    = (int*)  alloc((size_t)E * 4);
    unsigned short* h0 = (unsigned short*)alloc((size_t)N * 128 * 2);
    unsigned short* h1 = (unsigned short*)alloc((size_t)N * 128 * 2);

    const int gN = (N + 255) / 256;             // 391
    const int nPairs = N / 32;                  // 3125
    const int nTiles = N / 16;                  // 6250
    const int gAgg = 8 * ((N + 127) / 128);     // 8 panels x 782 node-chunks
    const int gPart = 2048;                     // 8 dst-range groups x 256 blocks (fill)

    // CSR build
    k_zero_cnt<<<gN, 256, 0, stream>>>(cnt, N);
    k_count<<<1568, 256, 0, stream>>>(dstIdx, cnt, E, N);
    k_scan_a<<<gN, 256, 0, stream>>>(cnt, rowptr, bsum, dis, N);
    k_scan_b<<<1, 512, 0, stream>>>(bsum, gN);
    k_scan_c<<<gN, 256, 0, stream>>>(rowptr, cursor, bsum, N);
    k_fill<<<gPart, 256, 0, stream>>>(srcIdx, dstIdx, cursor, csrc, E, N);

    // Layer 1
    k_gemm128_a32<<<768, 256, 0, stream>>>(x, W1, dis, h0, nPairs);
    k_agg<<<gAgg, 256, 0, stream>>>(h0, h1, dis, rowptr, cnt, csrc, b1, 1, N);
    // Layer 2
    k_gemm128_a16<<<768, 256, 0, stream>>>(h1, W2, dis, h0, nPairs);
    k_agg<<<gAgg, 256, 0, stream>>>(h0, h1, dis, rowptr, cnt, csrc, b2, 1, N);
    // Layer 3 (no relu)
    k_gemm128_a16<<<768, 256, 0, stream>>>(h1, W3, dis, h0, nPairs);
    k_agg<<<gAgg, 256, 0, stream>>>(h0, h1, dis, rowptr, cnt, csrc, b3, 0, N);
    // Head
    k_gemm_final<<<(nTiles + 3) / 4, 256, 0, stream>>>(h1, Wl, bl, (float*)d_out, nTiles);
}

// Round 4
// 618.441 us; speedup vs baseline: 1.2421x; 1.2421x over previous
//
#include <hip/hip_runtime.h>

// ---------- types & helpers ----------
typedef __attribute__((ext_vector_type(8))) short sh8;   // 8 x bf16 (4 VGPRs)
typedef __attribute__((ext_vector_type(4))) float f4;    // MFMA accum / float4

__device__ __forceinline__ float bf2f(unsigned short u) {
    union { unsigned int u; float f; } c; c.u = ((unsigned int)u) << 16; return c.f;
}
__device__ __forceinline__ unsigned short f2bf(float f) {
    union { float f; unsigned int u; } c; c.f = f;
    unsigned int x = c.u;
    unsigned int r = (x + 0x7fffu + ((x >> 16) & 1u)) >> 16;   // RNE
    return (unsigned short)r;
}
__device__ __forceinline__ void bfsplit(float x, short& hi, short& lo) {
    unsigned short h = f2bf(x);
    float r = x - bf2f(h);
    hi = (short)h;
    lo = (short)f2bf(r);
}

// ---------- CSR build ----------
__global__ void k_zero_cnt(int* cnt, int N) {
    int i = blockIdx.x * 256 + threadIdx.x;
    if (i < N) cnt[i] = 0;
}

__global__ void k_count(const int* __restrict__ dst, int* __restrict__ cnt, int E, int N) {
    int E4 = E >> 2;
    for (int i = blockIdx.x * 256 + threadIdx.x; i < E4; i += gridDim.x * 256) {
        int4 d = ((const int4*)dst)[i];
        if ((unsigned)d.x < (unsigned)N) atomicAdd(&cnt[d.x], 1);
        if ((unsigned)d.y < (unsigned)N) atomicAdd(&cnt[d.y], 1);
        if ((unsigned)d.z < (unsigned)N) atomicAdd(&cnt[d.z], 1);
        if ((unsigned)d.w < (unsigned)N) atomicAdd(&cnt[d.w], 1);
    }
    if (blockIdx.x == 0) {   // remainder edges
        for (int e = (E4 << 2) + threadIdx.x; e < E; e += 256) {
            int d = dst[e];
            if ((unsigned)d < (unsigned)N) atomicAdd(&cnt[d], 1);
        }
    }
}

#define SCAN_B 256
// also emits dis[i] = rsqrt(deg+1)
__global__ void k_scan_a(const int* __restrict__ cnt, int* __restrict__ rowptr,
                         int* __restrict__ bsum, float* __restrict__ dis, int N) {
    __shared__ int sh[SCAN_B];
    int t = threadIdx.x, i = blockIdx.x * SCAN_B + t;
    int v = (i < N) ? cnt[i] : 0;
    if (i < N) dis[i] = rsqrtf((float)(v + 1));   // +1 self loop
    sh[t] = v; __syncthreads();
    for (int off = 1; off < SCAN_B; off <<= 1) {
        int x = (t >= off) ? sh[t - off] : 0;
        __syncthreads();
        sh[t] += x;
        __syncthreads();
    }
    int incl = sh[t];
    if (i < N) rowptr[i] = incl - v;
    if (t == SCAN_B - 1) bsum[blockIdx.x] = incl;
}

__global__ void k_scan_b(int* bsum, int NB) {
    __shared__ int sh[512];
    int t = threadIdx.x;
    int v = (t < NB) ? bsum[t] : 0;
    sh[t] = v; __syncthreads();
    for (int off = 1; off < 512; off <<= 1) {
        int x = (t >= off) ? sh[t - off] : 0;
        __syncthreads();
        sh[t] += x;
        __syncthreads();
    }
    if (t < NB) bsum[t] = sh[t] - v;
}

__global__ void k_scan_c(int* __restrict__ rowptr, int* __restrict__ cursor,
                         const int* __restrict__ bsum, int N) {
    int i = blockIdx.x * 256 + threadIdx.x;
    if (i < N) {
        int r = rowptr[i] + bsum[blockIdx.x];
        rowptr[i] = r;
        cursor[i] = r;
    }
}

// ---------- FUSED: CSR fill (blocks [0,2048)) + layer-1 GEMM (blocks [2048,2816)) ----------
// fill: latency/scatter-bound, VALU ~4%; gemm1: MFMA-bound. Independent work -> co-run.
// Fill blocks first so the long pole starts immediately.
#define FILL_BLOCKS 2048
#define GEMM1_BLOCKS 768

__device__ __forceinline__ void fill_body(const int* __restrict__ src,
                                          const int* __restrict__ dst,
                                          int* __restrict__ cursor,
                                          int* __restrict__ csrc, int E, int N) {
    int bid = blockIdx.x;
    int g = bid & 7;
    int j = bid >> 3;
    int nb = FILL_BLOCKS >> 3;
    int lo = (int)((long long)g * N / 8);
    int hi = (int)((long long)(g + 1) * N / 8);
    int E4 = E >> 2;
    for (int i = j * 256 + threadIdx.x; i < E4; i += nb * 256) {
        int4 d4 = ((const int4*)dst)[i];
        int e = i << 2;
        #pragma unroll
        for (int q = 0; q < 4; ++q) {
            int d = (q == 0) ? d4.x : (q == 1) ? d4.y : (q == 2) ? d4.z : d4.w;
            if (d < lo || d >= hi) continue;
            int s = src[e + q];
            if ((unsigned)s >= (unsigned)N) continue;
            int p = atomicAdd(&cursor[d], 1);
            csrc[p] = s;
        }
    }
    if (bid == 0) {   // remainder edges: no range filter, handled once here
        for (int e = (E4 << 2) + threadIdx.x; e < E; e += 256) {
            int d = dst[e];
            int s = src[e];
            if ((unsigned)d >= (unsigned)N || (unsigned)s >= (unsigned)N) continue;
            int p = atomicAdd(&cursor[d], 1);
            csrc[p] = s;
        }
    }
}

__device__ __forceinline__ void gemm1_body(const float* __restrict__ X,
                                           const float* __restrict__ W,
                                           const float* __restrict__ dis,
                                           unsigned short* __restrict__ H, int nPairs) {
    int bid = blockIdx.x - FILL_BLOCKS;
    int wave = threadIdx.x >> 6;
    int lane = threadIdx.x & 63;
    int ln = lane & 15, quad = lane >> 4;
    int c0 = (wave & 1) * 64;
    int subTile = wave >> 1;

    sh8 bh[4][4], blo[4][4];   // [nt][kt]
    #pragma unroll
    for (int nt = 0; nt < 4; ++nt) {
        int col = c0 + nt * 16 + ln;
        #pragma unroll
        for (int kt = 0; kt < 4; ++kt) {
            int k0 = kt * 32 + quad * 8;
            #pragma unroll
            for (int j = 0; j < 8; ++j) {
                short h, l;
                bfsplit(W[(k0 + j) * 128 + col], h, l);
                bh[nt][kt][j] = h; blo[nt][kt][j] = l;
            }
        }
    }

    for (int p = bid; p < nPairs; p += GEMM1_BLOCKS) {
        int nodeBase = p * 32 + subTile * 16;
        const float* xrow = X + (nodeBase + ln) * 128 + quad * 8;
        sh8 ah[4], al[4];
        #pragma unroll
        for (int kt = 0; kt < 4; ++kt) {
            f4 v0 = *(const f4*)(xrow + kt * 32);
            f4 v1 = *(const f4*)(xrow + kt * 32 + 4);
            #pragma unroll
            for (int j = 0; j < 4; ++j) {
                short h, l;
                bfsplit(v0[j], h, l); ah[kt][j] = h; al[kt][j] = l;
                bfsplit(v1[j], h, l); ah[kt][j + 4] = h; al[kt][j + 4] = l;
            }
        }

        f4 acc[4] = { {0.f,0.f,0.f,0.f}, {0.f,0.f,0.f,0.f}, {0.f,0.f,0.f,0.f}, {0.f,0.f,0.f,0.f} };
        #pragma unroll
        for (int kt = 0; kt < 4; ++kt)
            #pragma unroll
            for (int nt = 0; nt < 4; ++nt) {
                acc[nt] = __builtin_amdgcn_mfma_f32_16x16x32_bf16(ah[kt], bh[nt][kt], acc[nt], 0, 0, 0);
                acc[nt] = __builtin_amdgcn_mfma_f32_16x16x32_bf16(ah[kt], blo[nt][kt], acc[nt], 0, 0, 0);
                acc[nt] = __builtin_amdgcn_mfma_f32_16x16x32_bf16(al[kt], bh[nt][kt], acc[nt], 0, 0, 0);
            }

        float ds[4];
        #pragma unroll
        for (int r = 0; r < 4; ++r) ds[r] = dis[nodeBase + quad * 4 + r];
        #pragma unroll
        for (int nt = 0; nt < 4; ++nt) {
            int col = c0 + nt * 16 + ln;
            #pragma unroll
            for (int r = 0; r < 4; ++r)
                H[(nodeBase + quad * 4 + r) * 128 + col] = f2bf(acc[nt][r] * ds[r]);
        }
    }
}

__global__ __launch_bounds__(256)
void k_fill_gemm1(const int* __restrict__ src, const int* __restrict__ dst,
                  int* __restrict__ cursor, int* __restrict__ csrc, int E, int N,
                  const float* __restrict__ X, const float* __restrict__ W,
                  const float* __restrict__ dis, unsigned short* __restrict__ H,
                  int nPairs) {
    if (blockIdx.x < FILL_BLOCKS)
        fill_body(src, dst, cursor, csrc, E, N);
    else
        gemm1_body(X, W, dis, H, nPairs);
}

// ---------- GEMM (layers 2,3): H(bf16) = (X(bf16) @ W(fp32, split)) * dis[row] ----------
__global__ __launch_bounds__(256)
void k_gemm128_a16(const unsigned short* __restrict__ X,
                   const float* __restrict__ W,
                   const float* __restrict__ dis,
                   unsigned short* __restrict__ H, int nPairs) {
    int wave = threadIdx.x >> 6;
    int lane = threadIdx.x & 63;
    int ln = lane & 15, quad = lane >> 4;
    int c0 = (wave & 1) * 64;
    int subTile = wave >> 1;

    sh8 bh[4][4], blo[4][4];
    #pragma unroll
    for (int nt = 0; nt < 4; ++nt) {
        int col = c0 + nt * 16 + ln;
        #pragma unroll
        for (int kt = 0; kt < 4; ++kt) {
            int k0 = kt * 32 + quad * 8;
            #pragma unroll
            for (int j = 0; j < 8; ++j) {
                short h, l;
                bfsplit(W[(k0 + j) * 128 + col], h, l);
                bh[nt][kt][j] = h; blo[nt][kt][j] = l;
            }
        }
    }

    for (int p = blockIdx.x; p < nPairs; p += gridDim.x) {
        int nodeBase = p * 32 + subTile * 16;
        const unsigned short* xrow = X + (nodeBase + ln) * 128 + quad * 8;
        sh8 a[4];
        #pragma unroll
        for (int kt = 0; kt < 4; ++kt) a[kt] = *(const sh8*)(xrow + kt * 32);

        f4 acc[4] = { {0.f,0.f,0.f,0.f}, {0.f,0.f,0.f,0.f}, {0.f,0.f,0.f,0.f}, {0.f,0.f,0.f,0.f} };
        #pragma unroll
        for (int kt = 0; kt < 4; ++kt)
            #pragma unroll
            for (int nt = 0; nt < 4; ++nt) {
                acc[nt] = __builtin_amdgcn_mfma_f32_16x16x32_bf16(a[kt], bh[nt][kt], acc[nt], 0, 0, 0);
                acc[nt] = __builtin_amdgcn_mfma_f32_16x16x32_bf16(a[kt], blo[nt][kt], acc[nt], 0, 0, 0);
            }

        float ds[4];
        #pragma unroll
        for (int r = 0; r < 4; ++r) ds[r] = dis[nodeBase + quad * 4 + r];
        #pragma unroll
        for (int nt = 0; nt < 4; ++nt) {
            int col = c0 + nt * 16 + ln;
            #pragma unroll
            for (int r = 0; r < 4; ++r)
                H[(nodeBase + quad * 4 + r) * 128 + col] = f2bf(acc[nt][r] * ds[r]);
        }
    }
}

// ---------- Aggregation v4: one HALF-WAVE (2 x 16 lanes) per node ----------
// H rows pre-scaled by dis[src] in the GEMM epilogue; inner loop is a pure bf16 sum:
// out[n] = dis[n] * (sum_{s in nbr} H'[s] + H'[n]) + b.
// Two 16-lane groups per node; each group loads a full 256B row as 16 x dwordx4,
// covering TWO edges per round; one shfl_xor(16) per accumulator at the end.
__global__ __launch_bounds__(256)
void k_agg(const unsigned short* __restrict__ H,
           unsigned short* __restrict__ O,
           const float* __restrict__ dis,
           const int* __restrict__ rowptr,
           const int* __restrict__ cnt,
           const int* __restrict__ csrc,
           const float* __restrict__ bias,
           int relu, int N) {
    int n = (blockIdx.x * 256 + threadIdx.x) >> 5;
    if (n >= N) return;
    int lane = threadIdx.x & 31;
    int sub  = lane & 15;      // feats sub*8 .. sub*8+7 (16B)
    int half = lane >> 4;      // which edge of each pair

    float a0 = 0.f, a1 = 0.f, a2 = 0.f, a3 = 0.f;
    float a4 = 0.f, a5 = 0.f, a6 = 0.f, a7 = 0.f;

    auto addrow = [&](uint4 v) {
        a0 += bf2f((unsigned short)v.x);
        a1 += bf2f((unsigned short)(v.x >> 16));
        a2 += bf2f((unsigned short)v.y);
        a3 += bf2f((unsigned short)(v.y >> 16));
        a4 += bf2f((unsigned short)v.z);
        a5 += bf2f((unsigned short)(v.z >> 16));
        a6 += bf2f((unsigned short)v.w);
        a7 += bf2f((unsigned short)(v.w >> 16));
    };

    if (half == 0)   // self loop (already scaled by dis[n]; final *dis[n] gives dn^2)
        addrow(*(const uint4*)(H + (size_t)n * 128 + sub * 8));

    int start = rowptr[n];
    int e = cnt[n];
    int i = 0;
    for (; i + 8 <= e; i += 8) {     // 8 edges per round, 4 per 16-lane group
        int s[4];
        #pragma unroll
        for (int q = 0; q < 4; ++q) s[q] = csrc[start + i + 2 * q + half];
        uint4 v[4];
        #pragma unroll
        for (int q = 0; q < 4; ++q) v[q] = *(const uint4*)(H + (size_t)s[q] * 128 + sub * 8);
        #pragma unroll
        for (int q = 0; q < 4; ++q) addrow(v[q]);
    }
    for (int j = i + half; j < e; j += 2) {
        int s = csrc[start + j];
        addrow(*(const uint4*)(H + (size_t)s * 128 + sub * 8));
    }

    a0 += __shfl_xor(a0, 16); a1 += __shfl_xor(a1, 16);
    a2 += __shfl_xor(a2, 16); a3 += __shfl_xor(a3, 16);
    a4 += __shfl_xor(a4, 16); a5 += __shfl_xor(a5, 16);
    a6 += __shfl_xor(a6, 16); a7 += __shfl_xor(a7, 16);

    if (half == 0) {
        float dn = dis[n];
        f4 b0 = *(const f4*)(bias + sub * 8);
        f4 b1 = *(const f4*)(bias + sub * 8 + 4);
        a0 = a0 * dn + b0[0]; a1 = a1 * dn + b0[1];
        a2 = a2 * dn + b0[2]; a3 = a3 * dn + b0[3];
        a4 = a4 * dn + b1[0]; a5 = a5 * dn + b1[1];
        a6 = a6 * dn + b1[2]; a7 = a7 * dn + b1[3];
        if (relu) {
            a0 = fmaxf(a0, 0.f); a1 = fmaxf(a1, 0.f);
            a2 = fmaxf(a2, 0.f); a3 = fmaxf(a3, 0.f);
            a4 = fmaxf(a4, 0.f); a5 = fmaxf(a5, 0.f);
            a6 = fmaxf(a6, 0.f); a7 = fmaxf(a7, 0.f);
        }
        uint4 ov;
        ov.x = (unsigned int)f2bf(a0) | ((unsigned int)f2bf(a1) << 16);
        ov.y = (unsigned int)f2bf(a2) | ((unsigned int)f2bf(a3) << 16);
        ov.z = (unsigned int)f2bf(a4) | ((unsigned int)f2bf(a5) << 16);
        ov.w = (unsigned int)f2bf(a6) | ((unsigned int)f2bf(a7) << 16);
        *(uint4*)(O + (size_t)n * 128 + sub * 8) = ov;
    }
}

// ---------- Final head: OUT[N][40](fp32) = X(bf16) @ Wl(fp32 split) + bl ----------
__global__ __launch_bounds__(256)
void k_gemm_final(const unsigned short* __restrict__ X,
                  const float* __restrict__ W,     // [128][40]
                  const float* __restrict__ bl,    // [40]
                  float* __restrict__ OUT, int nTiles) {
    int wave = threadIdx.x >> 6;
    int lane = threadIdx.x & 63;
    int ln = lane & 15, quad = lane >> 4;
    int tile = blockIdx.x * 4 + wave;
    if (tile >= nTiles) return;

    sh8 bh[3][4], blo[3][4];
    #pragma unroll
    for (int nt = 0; nt < 3; ++nt) {
        int col = nt * 16 + ln;
        bool valid = (col < 40);
        #pragma unroll
        for (int kt = 0; kt < 4; ++kt) {
            int k0 = kt * 32 + quad * 8;
            #pragma unroll
            for (int j = 0; j < 8; ++j) {
                short h = 0, l = 0;
                if (valid) bfsplit(W[(k0 + j) * 40 + col], h, l);
                bh[nt][kt][j] = h; blo[nt][kt][j] = l;
            }
        }
    }

    int nodeBase = tile * 16;
    const unsigned short* xrow = X + (nodeBase + ln) * 128 + quad * 8;
    sh8 a[4];
    #pragma unroll
    for (int kt = 0; kt < 4; ++kt) a[kt] = *(const sh8*)(xrow + kt * 32);

    f4 acc[3] = { {0.f,0.f,0.f,0.f}, {0.f,0.f,0.f,0.f}, {0.f,0.f,0.f,0.f} };
    #pragma unroll
    for (int kt = 0; kt < 4; ++kt)
        #pragma unroll
        for (int nt = 0; nt < 3; ++nt) {
            acc[nt] = __builtin_amdgcn_mfma_f32_16x16x32_bf16(a[kt], bh[nt][kt], acc[nt], 0, 0, 0);
            acc[nt] = __builtin_amdgcn_mfma_f32_16x16x32_bf16(a[kt], blo[nt][kt], acc[nt], 0, 0, 0);
        }

    #pragma unroll
    for (int nt = 0; nt < 3; ++nt) {
        int col = nt * 16 + ln;
        if (col < 40) {
            float bv = bl[col];
            #pragma unroll
            for (int r = 0; r < 4; ++r)
                OUT[(nodeBase + quad * 4 + r) * 40 + col] = acc[nt][r] + bv;
        }
    }
}

// ---------- launch ----------
extern "C" void kernel_launch(void* const* d_in, const int* in_sizes, int n_in,
                              void* d_out, int out_size, void* d_ws, size_t ws_size,
                              hipStream_t stream) {
    const float* x  = (const float*)d_in[0];
    const int*   ei = (const int*)d_in[1];
    const float* W1 = (const float*)d_in[2];
    const float* b1 = (const float*)d_in[3];
    const float* W2 = (const float*)d_in[4];
    const float* b2 = (const float*)d_in[5];
    const float* W3 = (const float*)d_in[6];
    const float* b3 = (const float*)d_in[7];
    const float* Wl = (const float*)d_in[8];
    const float* bl = (const float*)d_in[9];

    const int N = in_sizes[0] / 128;   // 100000
    const int E = in_sizes[1] / 2;     // 1600000
    const int* srcIdx = ei;
    const int* dstIdx = ei + E;

    char* ws = (char*)d_ws;
    size_t off = 0;
    auto alloc = [&](size_t bytes) { void* p = ws + off; off += (bytes + 511) & ~(size_t)511; return p; };
    int*   cnt     = (int*)  alloc((size_t)N * 4);
    int*   rowptr  = (int*)  alloc((size_t)N * 4);
    int*   cursor  = (int*)  alloc((size_t)N * 4);
    float* dis     = (float*)alloc((size_t)N * 4);
    int*   bsum    = (int*)  alloc(512 * 4);
    int*   csrc    = (int*)  alloc((size_t)E * 4);
    unsigned short* h0 = (unsigned short*)alloc((size_t)N * 128 * 2);
    unsigned short* h1 = (unsigned short*)alloc((size_t)N * 128 * 2);

    const int gN = (N + 255) / 256;           // 391
    const int nPairs = N / 32;                // 3125
    const int nTiles = N / 16;                // 6250
    const int gAgg = (N * 32 + 255) / 256;    // 12500 (half-wave per node)

    // CSR build (count/scan), then fused fill||gemm1
    k_zero_cnt<<<gN, 256, 0, stream>>>(cnt, N);
    k_count<<<1568, 256, 0, stream>>>(dstIdx, cnt, E, N);
    k_scan_a<<<gN, 256, 0, stream>>>(cnt, rowptr, bsum, dis, N);
    k_scan_b<<<1, 512, 0, stream>>>(bsum, gN);
    k_scan_c<<<gN, 256, 0, stream>>>(rowptr, cursor, bsum, N);

    // Fused: fill (blocks 0..2047) || layer-1 GEMM (blocks 2048..2815)
    k_fill_gemm1<<<FILL_BLOCKS + GEMM1_BLOCKS, 256, 0, stream>>>(
        srcIdx, dstIdx, cursor, csrc, E, N, x, W1, dis, h0, nPairs);

    // Layer 1 aggregation
    k_agg<<<gAgg, 256, 0, stream>>>(h0, h1, dis, rowptr, cnt, csrc, b1, 1, N);
    // Layer 2
    k_gemm128_a16<<<768, 256, 0, stream>>>(h1, W2, dis, h0, nPairs);
    k_agg<<<gAgg, 256, 0, stream>>>(h0, h1, dis, rowptr, cnt, csrc, b2, 1, N);
    // Layer 3 (no relu)
    k_gemm128_a16<<<768, 256, 0, stream>>>(h1, W3, dis, h0, nPairs);
    k_agg<<<gAgg, 256, 0, stream>>>(h0, h1, dis, rowptr, cnt, csrc, b3, 0, N);
    // Head
    k_gemm_final<<<(nTiles + 3) / 4, 256, 0, stream>>>(h1, Wl, bl, (float*)d_out, nTiles);
}

// Round 5
// 492.147 us; speedup vs baseline: 1.5609x; 1.2566x over previous
//
#include <hip/hip_runtime.h>

// ---------- types & helpers ----------
typedef __attribute__((ext_vector_type(8))) short sh8;   // 8 x bf16 (4 VGPRs)
typedef __attribute__((ext_vector_type(4))) float f4;    // MFMA accum / float4

__device__ __forceinline__ float bf2f(unsigned short u) {
    union { unsigned int u; float f; } c; c.u = ((unsigned int)u) << 16; return c.f;
}
__device__ __forceinline__ unsigned short f2bf(float f) {
    union { float f; unsigned int u; } c; c.f = f;
    unsigned int x = c.u;
    unsigned int r = (x + 0x7fffu + ((x >> 16) & 1u)) >> 16;   // RNE
    return (unsigned short)r;
}
__device__ __forceinline__ void bfsplit(float x, short& hi, short& lo) {
    unsigned short h = f2bf(x);
    float r = x - bf2f(h);
    hi = (short)h;
    lo = (short)f2bf(r);
}

// ---------- CSR build ----------
__global__ void k_zero_cnt(int* cnt, int N) {
    int i = blockIdx.x * 256 + threadIdx.x;
    if (i < N) cnt[i] = 0;
}

// Count degrees AND record each edge's rank among its dst's edges (the atomicAdd
// return value, previously discarded). rank enables an atomic-free fill.
__global__ void k_count(const int* __restrict__ dst, int* __restrict__ cnt,
                        int* __restrict__ rank, int E, int N) {
    int E4 = E >> 2;
    for (int i = blockIdx.x * 256 + threadIdx.x; i < E4; i += gridDim.x * 256) {
        int4 d = ((const int4*)dst)[i];
        int4 r;
        r.x = ((unsigned)d.x < (unsigned)N) ? atomicAdd(&cnt[d.x], 1) : -1;
        r.y = ((unsigned)d.y < (unsigned)N) ? atomicAdd(&cnt[d.y], 1) : -1;
        r.z = ((unsigned)d.z < (unsigned)N) ? atomicAdd(&cnt[d.z], 1) : -1;
        r.w = ((unsigned)d.w < (unsigned)N) ? atomicAdd(&cnt[d.w], 1) : -1;
        ((int4*)rank)[i] = r;
    }
    if (blockIdx.x == 0) {   // remainder edges
        for (int e = (E4 << 2) + threadIdx.x; e < E; e += 256) {
            int d = dst[e];
            rank[e] = ((unsigned)d < (unsigned)N) ? atomicAdd(&cnt[d], 1) : -1;
        }
    }
}

#define SCAN_B 256
// also emits dis[i] = rsqrt(deg+1)
__global__ void k_scan_a(const int* __restrict__ cnt, int* __restrict__ rowptr,
                         int* __restrict__ bsum, float* __restrict__ dis, int N) {
    __shared__ int sh[SCAN_B];
    int t = threadIdx.x, i = blockIdx.x * SCAN_B + t;
    int v = (i < N) ? cnt[i] : 0;
    if (i < N) dis[i] = rsqrtf((float)(v + 1));   // +1 self loop
    sh[t] = v; __syncthreads();
    for (int off = 1; off < SCAN_B; off <<= 1) {
        int x = (t >= off) ? sh[t - off] : 0;
        __syncthreads();
        sh[t] += x;
        __syncthreads();
    }
    int incl = sh[t];
    if (i < N) rowptr[i] = incl - v;
    if (t == SCAN_B - 1) bsum[blockIdx.x] = incl;
}

__global__ void k_scan_b(int* bsum, int NB) {
    __shared__ int sh[512];
    int t = threadIdx.x;
    int v = (t < NB) ? bsum[t] : 0;
    sh[t] = v; __syncthreads();
    for (int off = 1; off < 512; off <<= 1) {
        int x = (t >= off) ? sh[t - off] : 0;
        __syncthreads();
        sh[t] += x;
        __syncthreads();
    }
    if (t < NB) bsum[t] = sh[t] - v;
}

__global__ void k_scan_c(int* __restrict__ rowptr, const int* __restrict__ bsum, int N) {
    int i = blockIdx.x * 256 + threadIdx.x;
    if (i < N) rowptr[i] += bsum[blockIdx.x];
}

// ---------- Atomic-free CSR fill ----------
// csrc[rowptr[d] + rank[e]] = src[e]. One streaming pass (dst+src+rank int4),
// one read-only rowptr gather (L2-replicated), one scattered store. No atomics,
// no dst-range partitioning, no dependent RMW chain.
__global__ void k_fill(const int* __restrict__ src, const int* __restrict__ dst,
                       const int* __restrict__ rank, const int* __restrict__ rowptr,
                       int* __restrict__ csrc, int E, int N) {
    int E4 = E >> 2;
    for (int i = blockIdx.x * 256 + threadIdx.x; i < E4; i += gridDim.x * 256) {
        int4 d4 = ((const int4*)dst)[i];
        int4 s4 = ((const int4*)src)[i];
        int4 r4 = ((const int4*)rank)[i];
        #pragma unroll
        for (int q = 0; q < 4; ++q) {
            int d = (q == 0) ? d4.x : (q == 1) ? d4.y : (q == 2) ? d4.z : d4.w;
            int s = (q == 0) ? s4.x : (q == 1) ? s4.y : (q == 2) ? s4.z : s4.w;
            int r = (q == 0) ? r4.x : (q == 1) ? r4.y : (q == 2) ? r4.z : r4.w;
            if ((unsigned)d >= (unsigned)N || (unsigned)s >= (unsigned)N || r < 0) continue;
            csrc[rowptr[d] + r] = s;
        }
    }
    if (blockIdx.x == 0) {   // remainder edges
        for (int e = (E4 << 2) + threadIdx.x; e < E; e += 256) {
            int d = dst[e];
            int s = src[e];
            int r = rank[e];
            if ((unsigned)d >= (unsigned)N || (unsigned)s >= (unsigned)N || r < 0) continue;
            csrc[rowptr[d] + r] = s;
        }
    }
}

// ---------- GEMM (layer 1): H[N][128](bf16) = (X[N][128](fp32) @ W) * dis[row] ----------
__global__ __launch_bounds__(256)
void k_gemm128_a32(const float* __restrict__ X,
                   const float* __restrict__ W,
                   const float* __restrict__ dis,
                   unsigned short* __restrict__ H, int nPairs) {
    int wave = threadIdx.x >> 6;
    int lane = threadIdx.x & 63;
    int ln = lane & 15, quad = lane >> 4;
    int c0 = (wave & 1) * 64;
    int subTile = wave >> 1;

    sh8 bh[4][4], blo[4][4];   // [nt][kt]
    #pragma unroll
    for (int nt = 0; nt < 4; ++nt) {
        int col = c0 + nt * 16 + ln;
        #pragma unroll
        for (int kt = 0; kt < 4; ++kt) {
            int k0 = kt * 32 + quad * 8;
            #pragma unroll
            for (int j = 0; j < 8; ++j) {
                short h, l;
                bfsplit(W[(k0 + j) * 128 + col], h, l);
                bh[nt][kt][j] = h; blo[nt][kt][j] = l;
            }
        }
    }

    for (int p = blockIdx.x; p < nPairs; p += gridDim.x) {
        int nodeBase = p * 32 + subTile * 16;
        const float* xrow = X + (nodeBase + ln) * 128 + quad * 8;
        sh8 ah[4], al[4];
        #pragma unroll
        for (int kt = 0; kt < 4; ++kt) {
            f4 v0 = *(const f4*)(xrow + kt * 32);
            f4 v1 = *(const f4*)(xrow + kt * 32 + 4);
            #pragma unroll
            for (int j = 0; j < 4; ++j) {
                short h, l;
                bfsplit(v0[j], h, l); ah[kt][j] = h; al[kt][j] = l;
                bfsplit(v1[j], h, l); ah[kt][j + 4] = h; al[kt][j + 4] = l;
            }
        }

        f4 acc[4] = { {0.f,0.f,0.f,0.f}, {0.f,0.f,0.f,0.f}, {0.f,0.f,0.f,0.f}, {0.f,0.f,0.f,0.f} };
        #pragma unroll
        for (int kt = 0; kt < 4; ++kt)
            #pragma unroll
            for (int nt = 0; nt < 4; ++nt) {
                acc[nt] = __builtin_amdgcn_mfma_f32_16x16x32_bf16(ah[kt], bh[nt][kt], acc[nt], 0, 0, 0);
                acc[nt] = __builtin_amdgcn_mfma_f32_16x16x32_bf16(ah[kt], blo[nt][kt], acc[nt], 0, 0, 0);
                acc[nt] = __builtin_amdgcn_mfma_f32_16x16x32_bf16(al[kt], bh[nt][kt], acc[nt], 0, 0, 0);
            }

        float ds[4];
        #pragma unroll
        for (int r = 0; r < 4; ++r) ds[r] = dis[nodeBase + quad * 4 + r];
        #pragma unroll
        for (int nt = 0; nt < 4; ++nt) {
            int col = c0 + nt * 16 + ln;
            #pragma unroll
            for (int r = 0; r < 4; ++r)
                H[(nodeBase + quad * 4 + r) * 128 + col] = f2bf(acc[nt][r] * ds[r]);
        }
    }
}

// ---------- GEMM (layers 2,3): H(bf16) = (X(bf16) @ W(fp32, split)) * dis[row] ----------
__global__ __launch_bounds__(256)
void k_gemm128_a16(const unsigned short* __restrict__ X,
                   const float* __restrict__ W,
                   const float* __restrict__ dis,
                   unsigned short* __restrict__ H, int nPairs) {
    int wave = threadIdx.x >> 6;
    int lane = threadIdx.x & 63;
    int ln = lane & 15, quad = lane >> 4;
    int c0 = (wave & 1) * 64;
    int subTile = wave >> 1;

    sh8 bh[4][4], blo[4][4];
    #pragma unroll
    for (int nt = 0; nt < 4; ++nt) {
        int col = c0 + nt * 16 + ln;
        #pragma unroll
        for (int kt = 0; kt < 4; ++kt) {
            int k0 = kt * 32 + quad * 8;
            #pragma unroll
            for (int j = 0; j < 8; ++j) {
                short h, l;
                bfsplit(W[(k0 + j) * 128 + col], h, l);
                bh[nt][kt][j] = h; blo[nt][kt][j] = l;
            }
        }
    }

    for (int p = blockIdx.x; p < nPairs; p += gridDim.x) {
        int nodeBase = p * 32 + subTile * 16;
        const unsigned short* xrow = X + (nodeBase + ln) * 128 + quad * 8;
        sh8 a[4];
        #pragma unroll
        for (int kt = 0; kt < 4; ++kt) a[kt] = *(const sh8*)(xrow + kt * 32);

        f4 acc[4] = { {0.f,0.f,0.f,0.f}, {0.f,0.f,0.f,0.f}, {0.f,0.f,0.f,0.f}, {0.f,0.f,0.f,0.f} };
        #pragma unroll
        for (int kt = 0; kt < 4; ++kt)
            #pragma unroll
            for (int nt = 0; nt < 4; ++nt) {
                acc[nt] = __builtin_amdgcn_mfma_f32_16x16x32_bf16(a[kt], bh[nt][kt], acc[nt], 0, 0, 0);
                acc[nt] = __builtin_amdgcn_mfma_f32_16x16x32_bf16(a[kt], blo[nt][kt], acc[nt], 0, 0, 0);
            }

        float ds[4];
        #pragma unroll
        for (int r = 0; r < 4; ++r) ds[r] = dis[nodeBase + quad * 4 + r];
        #pragma unroll
        for (int nt = 0; nt < 4; ++nt) {
            int col = c0 + nt * 16 + ln;
            #pragma unroll
            for (int r = 0; r < 4; ++r)
                H[(nodeBase + quad * 4 + r) * 128 + col] = f2bf(acc[nt][r] * ds[r]);
        }
    }
}

// ---------- Aggregation: one HALF-WAVE (2 x 16 lanes) per node ----------
// H rows pre-scaled by dis[src] in the GEMM epilogue; inner loop is a pure bf16 sum:
// out[n] = dis[n] * (sum_{s in nbr} H'[s] + H'[n]) + b.
// Two 16-lane groups per node; each group loads a full 256B row as 16 x dwordx4,
// covering TWO edges per round; one shfl_xor(16) per accumulator at the end.
__global__ __launch_bounds__(256)
void k_agg(const unsigned short* __restrict__ H,
           unsigned short* __restrict__ O,
           const float* __restrict__ dis,
           const int* __restrict__ rowptr,
           const int* __restrict__ cnt,
           const int* __restrict__ csrc,
           const float* __restrict__ bias,
           int relu, int N) {
    int n = (blockIdx.x * 256 + threadIdx.x) >> 5;
    if (n >= N) return;
    int lane = threadIdx.x & 31;
    int sub  = lane & 15;      // feats sub*8 .. sub*8+7 (16B)
    int half = lane >> 4;      // which edge of each pair

    float a0 = 0.f, a1 = 0.f, a2 = 0.f, a3 = 0.f;
    float a4 = 0.f, a5 = 0.f, a6 = 0.f, a7 = 0.f;

    auto addrow = [&](uint4 v) {
        a0 += bf2f((unsigned short)v.x);
        a1 += bf2f((unsigned short)(v.x >> 16));
        a2 += bf2f((unsigned short)v.y);
        a3 += bf2f((unsigned short)(v.y >> 16));
        a4 += bf2f((unsigned short)v.z);
        a5 += bf2f((unsigned short)(v.z >> 16));
        a6 += bf2f((unsigned short)v.w);
        a7 += bf2f((unsigned short)(v.w >> 16));
    };

    if (half == 0)   // self loop (already scaled by dis[n]; final *dis[n] gives dn^2)
        addrow(*(const uint4*)(H + (size_t)n * 128 + sub * 8));

    int start = rowptr[n];
    int e = cnt[n];
    int i = 0;
    for (; i + 8 <= e; i += 8) {     // 8 edges per round, 4 per 16-lane group
        int s[4];
        #pragma unroll
        for (int q = 0; q < 4; ++q) s[q] = csrc[start + i + 2 * q + half];
        uint4 v[4];
        #pragma unroll
        for (int q = 0; q < 4; ++q) v[q] = *(const uint4*)(H + (size_t)s[q] * 128 + sub * 8);
        #pragma unroll
        for (int q = 0; q < 4; ++q) addrow(v[q]);
    }
    for (int j = i + half; j < e; j += 2) {
        int s = csrc[start + j];
        addrow(*(const uint4*)(H + (size_t)s * 128 + sub * 8));
    }

    a0 += __shfl_xor(a0, 16); a1 += __shfl_xor(a1, 16);
    a2 += __shfl_xor(a2, 16); a3 += __shfl_xor(a3, 16);
    a4 += __shfl_xor(a4, 16); a5 += __shfl_xor(a5, 16);
    a6 += __shfl_xor(a6, 16); a7 += __shfl_xor(a7, 16);

    if (half == 0) {
        float dn = dis[n];
        f4 b0 = *(const f4*)(bias + sub * 8);
        f4 b1 = *(const f4*)(bias + sub * 8 + 4);
        a0 = a0 * dn + b0[0]; a1 = a1 * dn + b0[1];
        a2 = a2 * dn + b0[2]; a3 = a3 * dn + b0[3];
        a4 = a4 * dn + b1[0]; a5 = a5 * dn + b1[1];
        a6 = a6 * dn + b1[2]; a7 = a7 * dn + b1[3];
        if (relu) {
            a0 = fmaxf(a0, 0.f); a1 = fmaxf(a1, 0.f);
            a2 = fmaxf(a2, 0.f); a3 = fmaxf(a3, 0.f);
            a4 = fmaxf(a4, 0.f); a5 = fmaxf(a5, 0.f);
            a6 = fmaxf(a6, 0.f); a7 = fmaxf(a7, 0.f);
        }
        uint4 ov;
        ov.x = (unsigned int)f2bf(a0) | ((unsigned int)f2bf(a1) << 16);
        ov.y = (unsigned int)f2bf(a2) | ((unsigned int)f2bf(a3) << 16);
        ov.z = (unsigned int)f2bf(a4) | ((unsigned int)f2bf(a5) << 16);
        ov.w = (unsigned int)f2bf(a6) | ((unsigned int)f2bf(a7) << 16);
        *(uint4*)(O + (size_t)n * 128 + sub * 8) = ov;
    }
}

// ---------- Final head: OUT[N][40](fp32) = X(bf16) @ Wl(fp32 split) + bl ----------
__global__ __launch_bounds__(256)
void k_gemm_final(const unsigned short* __restrict__ X,
                  const float* __restrict__ W,     // [128][40]
                  const float* __restrict__ bl,    // [40]
                  float* __restrict__ OUT, int nTiles) {
    int wave = threadIdx.x >> 6;
    int lane = threadIdx.x & 63;
    int ln = lane & 15, quad = lane >> 4;
    int tile = blockIdx.x * 4 + wave;
    if (tile >= nTiles) return;

    sh8 bh[3][4], blo[3][4];
    #pragma unroll
    for (int nt = 0; nt < 3; ++nt) {
        int col = nt * 16 + ln;
        bool valid = (col < 40);
        #pragma unroll
        for (int kt = 0; kt < 4; ++kt) {
            int k0 = kt * 32 + quad * 8;
            #pragma unroll
            for (int j = 0; j < 8; ++j) {
                short h = 0, l = 0;
                if (valid) bfsplit(W[(k0 + j) * 40 + col], h, l);
                bh[nt][kt][j] = h; blo[nt][kt][j] = l;
            }
        }
    }

    int nodeBase = tile * 16;
    const unsigned short* xrow = X + (nodeBase + ln) * 128 + quad * 8;
    sh8 a[4];
    #pragma unroll
    for (int kt = 0; kt < 4; ++kt) a[kt] = *(const sh8*)(xrow + kt * 32);

    f4 acc[3] = { {0.f,0.f,0.f,0.f}, {0.f,0.f,0.f,0.f}, {0.f,0.f,0.f,0.f} };
    #pragma unroll
    for (int kt = 0; kt < 4; ++kt)
        #pragma unroll
        for (int nt = 0; nt < 3; ++nt) {
            acc[nt] = __builtin_amdgcn_mfma_f32_16x16x32_bf16(a[kt], bh[nt][kt], acc[nt], 0, 0, 0);
            acc[nt] = __builtin_amdgcn_mfma_f32_16x16x32_bf16(a[kt], blo[nt][kt], acc[nt], 0, 0, 0);
        }

    #pragma unroll
    for (int nt = 0; nt < 3; ++nt) {
        int col = nt * 16 + ln;
        if (col < 40) {
            float bv = bl[col];
            #pragma unroll
            for (int r = 0; r < 4; ++r)
                OUT[(nodeBase + quad * 4 + r) * 40 + col] = acc[nt][r] + bv;
        }
    }
}

// ---------- launch ----------
extern "C" void kernel_launch(void* const* d_in, const int* in_sizes, int n_in,
                              void* d_out, int out_size, void* d_ws, size_t ws_size,
                              hipStream_t stream) {
    const float* x  = (const float*)d_in[0];
    const int*   ei = (const int*)d_in[1];
    const float* W1 = (const float*)d_in[2];
    const float* b1 = (const float*)d_in[3];
    const float* W2 = (const float*)d_in[4];
    const float* b2 = (const float*)d_in[5];
    const float* W3 = (const float*)d_in[6];
    const float* b3 = (const float*)d_in[7];
    const float* Wl = (const float*)d_in[8];
    const float* bl = (const float*)d_in[9];

    const int N = in_sizes[0] / 128;   // 100000
    const int E = in_sizes[1] / 2;     // 1600000
    const int* srcIdx = ei;
    const int* dstIdx = ei + E;

    char* ws = (char*)d_ws;
    size_t off = 0;
    auto alloc = [&](size_t bytes) { void* p = ws + off; off += (bytes + 511) & ~(size_t)511; return p; };
    int*   cnt     = (int*)  alloc((size_t)N * 4);
    int*   rowptr  = (int*)  alloc((size_t)N * 4);
    float* dis     = (float*)alloc((size_t)N * 4);
    int*   bsum    = (int*)  alloc(512 * 4);
    int*   csrc    = (int*)  alloc((size_t)E * 4);
    unsigned short* h0 = (unsigned short*)alloc((size_t)N * 128 * 2);
    unsigned short* h1 = (unsigned short*)alloc((size_t)N * 128 * 2);
    // rank (E ints = 6.4MB) aliases h0 (25.6MB): rank is consumed by k_fill, which
    // completes before gemm1 (the first writer of h0) launches on the same stream.
    int* rank = (int*)h0;

    const int gN = (N + 255) / 256;           // 391
    const int nPairs = N / 32;                // 3125
    const int nTiles = N / 16;                // 6250
    const int gAgg = (N * 32 + 255) / 256;    // 12500 (half-wave per node)

    // CSR build: count (emitting ranks) -> scan -> atomic-free fill
    k_zero_cnt<<<gN, 256, 0, stream>>>(cnt, N);
    k_count<<<1568, 256, 0, stream>>>(dstIdx, cnt, rank, E, N);
    k_scan_a<<<gN, 256, 0, stream>>>(cnt, rowptr, bsum, dis, N);
    k_scan_b<<<1, 512, 0, stream>>>(bsum, gN);
    k_scan_c<<<gN, 256, 0, stream>>>(rowptr, bsum, N);
    k_fill<<<1568, 256, 0, stream>>>(srcIdx, dstIdx, rank, rowptr, csrc, E, N);

    // Layer 1
    k_gemm128_a32<<<768, 256, 0, stream>>>(x, W1, dis, h0, nPairs);
    k_agg<<<gAgg, 256, 0, stream>>>(h0, h1, dis, rowptr, cnt, csrc, b1, 1, N);
    // Layer 2
    k_gemm128_a16<<<768, 256, 0, stream>>>(h1, W2, dis, h0, nPairs);
    k_agg<<<gAgg, 256, 0, stream>>>(h0, h1, dis, rowptr, cnt, csrc, b2, 1, N);
    // Layer 3 (no relu)
    k_gemm128_a16<<<768, 256, 0, stream>>>(h1, W3, dis, h0, nPairs);
    k_agg<<<gAgg, 256, 0, stream>>>(h0, h1, dis, rowptr, cnt, csrc, b3, 0, N);
    // Head
    k_gemm_final<<<(nTiles + 3) / 4, 256, 0, stream>>>(h1, Wl, bl, (float*)d_out, nTiles);
}